// Round 10
// baseline (207.117 us; speedup 1.0000x reference)
//
#include <hip/hip_runtime.h>
#include <hip/hip_bf16.h>
#include <stdint.h>

// Per-edge MLP  out = relu(relu([h[src],h[dst]] @ W1.T + b1) @ W2.T + b2) @ W3.T + b3
// N=100000, H=128, E=1.6M, layers 256->64->32->6, fp32 in/out.
//
// Pipeline:
//  0) prep_weights: W1 -> Bfrag (node_gemm B-frags); W2 -> A-form frags with row
//     permutation phi (see below); W3 -> B-frag (cols 6..15 zero).
//  1) node_gemm (MFMA): pre[n] = [h@W1a.T + b1 , h@W1b.T] bf16 (25.6MB, L3-res).
//  2) edge_mlp (MFMA): per-wave loop over 32-edge groups with ASYNC LDS-staged
//     gathers (global_load_lds, 16B/lane, zero VGPR cost -- R5/R8/R9 showed the
//     register allocator never keeps >4 register gathers in flight; 3 rounds
//     pinned at 69us latency-bound). Iteration: [8 ds_read_b128 of group g,
//     conflict-free: lane reads back its own staged 16B] -> [issue 8 async
//     loads for g+1 + idx prefetch g+2] -> sched_barrier -> [compute g].
//     vmcnt(0) is auto-inserted only at the loop top (correct wait), and the
//     g+1 loads ride out during compute.
//
// Layer-2 transpose trick (kills the zbuf LDS transpose + its 400K bank
// conflicts): compute z^T = W2 . y^T with W2 as the MFMA **A** operand
// (rows permuted by phi_nt(m) = (m>>2)*8 + (m&3) + 4*nt) and y as **B**
// (gather layout is identical for A/B frags). Then lane(m15,quad) receives
// z features quad*8..+7 of edge m15 across the two ntile accumulators --
// exactly the layer-3 A-fragment, packed in-register. No LDS, no barriers.
// MFMA 16x16x32_bf16 layouts (m89/m91-verified):
//   A[m=lane&15][k=(lane>>4)*8+j], B[k=(lane>>4)*8+j][n=lane&15],
//   C/D: col=lane&15, row=(lane>>4)*4+reg.

#define H 128

typedef short bf16x8 __attribute__((ext_vector_type(8)));
typedef float f32x4  __attribute__((ext_vector_type(4)));

typedef const __attribute__((address_space(1))) void gas_void;
typedef __attribute__((address_space(3))) void las_void;
__device__ __forceinline__ void async_copy16(const void* g, void* l) {
    __builtin_amdgcn_global_load_lds((gas_void*)g, (las_void*)l, 16, 0, 0);
}

__device__ __forceinline__ uint16_t f2bf(float f) {           // RNE fp32->bf16
    uint32_t u = __float_as_uint(f);
    return (uint16_t)((u + 0x7fffu + ((u >> 16) & 1u)) >> 16);
}
__device__ __forceinline__ uint32_t pk_bf16(float lo, float hi) {   // RNE pair pack
    __hip_bfloat162 v = __float22bfloat162_rn(float2{lo, hi});
    return *reinterpret_cast<uint32_t*>(&v);
}
__device__ __forceinline__ uint32_t bfadd2_relu(uint32_t a, uint32_t b) {
    __hip_bfloat162 x = *reinterpret_cast<__hip_bfloat162*>(&a);
    __hip_bfloat162 y = *reinterpret_cast<__hip_bfloat162*>(&b);
    __hip_bfloat162 s = __hadd2(x, y);
    uint32_t zu = 0u;                                  // packed bf16 {+0, +0}
    __hip_bfloat162 zero = *reinterpret_cast<__hip_bfloat162*>(&zu);
    __hip_bfloat162 r = __hmax2(s, zero);
    return *reinterpret_cast<uint32_t*>(&r);
}

// ---------------- weight prep ------------------------------------------------
// Bfrag: concat-W1 in B-frag order (node_gemm), 4 ktiles x 8 ntiles (32 KB).
// EFrag (edge_mlp), 5 frags x 64 lanes x 8 bf16:
//   f = nt*2+kt (f<4): layer-2 W2 in **A-frag** form with permuted rows:
//     A[m=lane&15][k] = W2[phi_nt(m)][kt*32+(lane>>4)*8+j],
//     phi_nt(m) = (m>>2)*8 + (m&3) + 4*nt
//   f=4: layer-3 B-frag: B[k=(lane>>4)*8+j][n=lane&15] = (n<6)? W3[n][k] : 0
__global__ void prep_weights(const float* __restrict__ W1,
                             const float* __restrict__ W2,
                             const float* __restrict__ W3,
                             uint16_t* __restrict__ Bfrag,
                             uint16_t* __restrict__ EFrag)
{
    int t = blockIdx.x * blockDim.x + threadIdx.x;
    int stride = gridDim.x * blockDim.x;
    for (int i = t; i < 4 * 8 * 64 * 8; i += stride) {
        int j    = i & 7;
        int lane = (i >> 3) & 63;
        int nt   = (i >> 9) & 7;
        int kt   = (i >> 12);
        int k = kt * 32 + (lane >> 4) * 8 + j;
        int n = nt * 16 + (lane & 15);
        float v = (n < 64) ? W1[n * 256 + k] : W1[(n - 64) * 256 + 128 + k];
        Bfrag[i] = f2bf(v);
    }
    for (int i = t; i < 5 * 64 * 8; i += stride) {
        int j    = i & 7;
        int lane = (i >> 3) & 63;
        int f    = i >> 9;
        uint16_t v;
        if (f < 4) {
            int nt = f >> 1, kt = f & 1;
            int m  = lane & 15;
            int row = (m >> 2) * 8 + (m & 3) + 4 * nt;        // phi_nt(m)
            int col = kt * 32 + (lane >> 4) * 8 + j;
            v = f2bf(W2[row * 64 + col]);
        } else {
            int k = (lane >> 4) * 8 + j;
            int n = lane & 15;
            v = (n < 6) ? f2bf(W3[n * 32 + k]) : (uint16_t)0;
        }
        EFrag[i] = v;
    }
}

// ---------------- per-node precompute (unchanged from R8) --------------------
__global__ void __launch_bounds__(256) node_gemm(
    const float* __restrict__ h,
    const uint16_t* __restrict__ Bfrag,
    const float* __restrict__ b1,
    uint16_t* __restrict__ pre, int N)
{
    const int wave = threadIdx.x >> 6;
    const int lane = threadIdx.x & 63;
    const int n0 = (blockIdx.x * 4 + wave) * 32;
    if (n0 >= N) return;

    const int m    = lane & 15;
    const int quad = lane >> 4;

    bf16x8 afr[2][4];
#pragma unroll
    for (int mt = 0; mt < 2; mt++) {
        int arow = n0 + mt * 16 + m; if (arow >= N) arow = N - 1;  // stores guarded
        const float* hrow = h + (size_t)arow * H + quad * 8;
#pragma unroll
        for (int kt = 0; kt < 4; kt++) {
            float4 lo = *(const float4*)(hrow + kt * 32);
            float4 hi = *(const float4*)(hrow + kt * 32 + 4);
            union { bf16x8 v; uint32_t u[4]; } A;
            A.u[0] = pk_bf16(lo.x, lo.y); A.u[1] = pk_bf16(lo.z, lo.w);
            A.u[2] = pk_bf16(hi.x, hi.y); A.u[3] = pk_bf16(hi.z, hi.w);
            afr[mt][kt] = A.v;
        }
    }

#pragma unroll
    for (int nt = 0; nt < 8; nt++) {
        const int n = nt * 16 + m;
        f32x4 acc0 = {0.f, 0.f, 0.f, 0.f};
        f32x4 acc1 = {0.f, 0.f, 0.f, 0.f};
#pragma unroll
        for (int kt = 0; kt < 4; kt++) {
            bf16x8 bfr = *(const bf16x8*)(Bfrag + ((size_t)(kt * 8 + nt) * 64 + lane) * 8);
            acc0 = __builtin_amdgcn_mfma_f32_16x16x32_bf16(afr[0][kt], bfr, acc0, 0, 0, 0);
            acc1 = __builtin_amdgcn_mfma_f32_16x16x32_bf16(afr[1][kt], bfr, acc1, 0, 0, 0);
        }
        const float bv = (n < 64) ? b1[n] : 0.f;
#pragma unroll
        for (int r = 0; r < 4; r++) {
            const int node0 = n0 + quad * 4 + r;
            if (node0 < N) pre[(size_t)node0 * H + n] = f2bf(acc0[r] + bv);
            const int node1 = n0 + 16 + quad * 4 + r;
            if (node1 < N) pre[(size_t)node1 * H + n] = f2bf(acc1[r] + bv);
        }
    }
}

// ---------------- per-edge MLP: async-staged, pipelined, LDS-transpose-free --
// Block = 128 threads = 2 waves; 32 KB staging (2 waves x 2 bufs x 8 KB)
// -> 5 blocks/CU. Wave loops over 32-edge groups with stride = total waves.
__global__ void __launch_bounds__(128) edge_mlp(
    const uint16_t* __restrict__ pre,
    const int* __restrict__ src, const int* __restrict__ dst,
    const uint16_t* __restrict__ EFrag,
    const float* __restrict__ b2, const float* __restrict__ b3,
    float* __restrict__ out, long E)
{
    __shared__ char stage[2][2][8192];   // [wave][buf][32 edges x 256 B]

    const int wave = threadIdx.x >> 6;
    const int lane = threadIdx.x & 63;
    const int m15  = lane & 15;
    const int quad = lane >> 4;

    char* bufs[2] = { &stage[wave][0][0], &stage[wave][1][0] };

    // Weights: W2-as-A frags (f=nt*2+kt), W3 B-frag; per-lane biases.
    bf16x8 w2a[4], bL3;
#pragma unroll
    for (int f = 0; f < 4; f++) w2a[f] = *(const bf16x8*)(EFrag + (f * 64 + lane) * 8);
    bL3 = *(const bf16x8*)(EFrag + (4 * 64 + lane) * 8);
    float vb2j[8];
    {
        float4 t0 = *(const float4*)(b2 + quad * 8);
        float4 t1 = *(const float4*)(b2 + quad * 8 + 4);
        vb2j[0] = t0.x; vb2j[1] = t0.y; vb2j[2] = t0.z; vb2j[3] = t0.w;
        vb2j[4] = t1.x; vb2j[5] = t1.y; vb2j[6] = t1.z; vb2j[7] = t1.w;
    }
    const float vb3 = (m15 < 6) ? b3[m15] : 0.f;

    const long ngroups = (E + 31) / 32;
    const long wid = (long)blockIdx.x * 2 + wave;
    const long nw  = (long)gridDim.x * 2;
    if (wid >= ngroups) return;

    const char* preb = (const char*)pre;
    const uint32_t q16 = (uint32_t)quad * 16u;

    // Index load for group g: lane needs edges g*32+m15 and g*32+16+m15
    // (all quads duplicate -> broadcast lines). Offsets include side bias.
#define LOADIDX(G, S0, S1, D0, D1)                                              \
    {                                                                           \
        long _e0 = (G) * 32;                                                    \
        long _ea = _e0 + m15;      if (_ea >= E) _ea = E - 1;                   \
        long _eb = _e0 + 16 + m15; if (_eb >= E) _eb = E - 1;                   \
        S0 = (uint32_t)src[_ea] * 256u;                                         \
        S1 = (uint32_t)src[_eb] * 256u;                                         \
        D0 = (uint32_t)dst[_ea] * 256u + 128u;                                  \
        D1 = (uint32_t)dst[_eb] * 256u + 128u;                                  \
    }

    // Issue 8 async 16B/lane copies for one group into buf.
    // Slab order: (st*2+side)*2+kt, 1 KB each; lane's chunk lands at lane*16.
#define ISSUE(S0, S1, D0, D1, BUF)                                              \
    {                                                                           \
        async_copy16(preb + S0 + q16,       (BUF) + 0 * 1024);                  \
        async_copy16(preb + S0 + 64 + q16,  (BUF) + 1 * 1024);                  \
        async_copy16(preb + D0 + q16,       (BUF) + 2 * 1024);                  \
        async_copy16(preb + D0 + 64 + q16,  (BUF) + 3 * 1024);                  \
        async_copy16(preb + S1 + q16,       (BUF) + 4 * 1024);                  \
        async_copy16(preb + S1 + 64 + q16,  (BUF) + 5 * 1024);                  \
        async_copy16(preb + D1 + q16,       (BUF) + 6 * 1024);                  \
        async_copy16(preb + D1 + 64 + q16,  (BUF) + 7 * 1024);                  \
    }

    // Prologue: group wid -> buf0; prefetch indices for wid+nw.
    uint32_t i1s0, i1s1, i1d0, i1d1;
    {
        uint32_t s0, s1, d0, d1;
        LOADIDX(wid, s0, s1, d0, d1)
        ISSUE(s0, s1, d0, d1, bufs[0])
        long g1 = wid + nw; if (g1 >= ngroups) g1 = ngroups - 1;
        LOADIDX(g1, i1s0, i1s1, i1d0, i1d1)
    }

    int p = 0;
    for (long g = wid; g < ngroups; g += nw) {
        char* bufc = bufs[p];
        char* bufn = bufs[p ^ 1];
        const long gn = g + nw;

        // ---- phase 1: read staged group g (conflict-free, lane*16) ----------
        uint4 ra[2][2], rb[2][2];   // [st][kt]
#pragma unroll
        for (int st = 0; st < 2; st++) {
#pragma unroll
            for (int kt = 0; kt < 2; kt++) {
                ra[st][kt] = *(const uint4*)(bufc + ((st * 2 + 0) * 2 + kt) * 1024 + lane * 16);
                rb[st][kt] = *(const uint4*)(bufc + ((st * 2 + 1) * 2 + kt) * 1024 + lane * 16);
            }
        }

        // ---- phase 2: launch group g+1 async; prefetch indices for g+2 ------
        if (gn < ngroups) {
            uint32_t s0 = i1s0, s1 = i1s1, d0 = i1d0, d1 = i1d1;
            ISSUE(s0, s1, d0, d1, bufn)
        }
        {
            long g2 = gn + nw; if (g2 >= ngroups) g2 = ngroups - 1;
            LOADIDX(g2, i1s0, i1s1, i1d0, i1d1)
        }
        __builtin_amdgcn_sched_barrier(0);   // keep async issues ahead of compute

        // ---- phase 3: y-build -> layer2 (z^T, W2-as-A) -> layer3 -> store ---
#pragma unroll
        for (int st = 0; st < 2; st++) {
            union { bf16x8 v; uint32_t u[4]; } Y0, Y1;   // y B-frags, kt=0/1
            Y0.u[0] = bfadd2_relu(ra[st][0].x, rb[st][0].x);
            Y0.u[1] = bfadd2_relu(ra[st][0].y, rb[st][0].y);
            Y0.u[2] = bfadd2_relu(ra[st][0].z, rb[st][0].z);
            Y0.u[3] = bfadd2_relu(ra[st][0].w, rb[st][0].w);
            Y1.u[0] = bfadd2_relu(ra[st][1].x, rb[st][1].x);
            Y1.u[1] = bfadd2_relu(ra[st][1].y, rb[st][1].y);
            Y1.u[2] = bfadd2_relu(ra[st][1].z, rb[st][1].z);
            Y1.u[3] = bfadd2_relu(ra[st][1].w, rb[st][1].w);

            f32x4 z0 = {0.f, 0.f, 0.f, 0.f};   // ntile 0: features quad*8 + r
            f32x4 z1 = {0.f, 0.f, 0.f, 0.f};   // ntile 1: features quad*8 + 4 + r
            z0 = __builtin_amdgcn_mfma_f32_16x16x32_bf16(w2a[0], Y0.v, z0, 0, 0, 0);
            z0 = __builtin_amdgcn_mfma_f32_16x16x32_bf16(w2a[1], Y1.v, z0, 0, 0, 0);
            z1 = __builtin_amdgcn_mfma_f32_16x16x32_bf16(w2a[2], Y0.v, z1, 0, 0, 0);
            z1 = __builtin_amdgcn_mfma_f32_16x16x32_bf16(w2a[3], Y1.v, z1, 0, 0, 0);

            // relu(z + b2) packed straight into the layer-3 A-fragment.
            union { bf16x8 v; uint32_t u[4]; } A3;
            A3.u[0] = pk_bf16(fmaxf(z0[0] + vb2j[0], 0.f), fmaxf(z0[1] + vb2j[1], 0.f));
            A3.u[1] = pk_bf16(fmaxf(z0[2] + vb2j[2], 0.f), fmaxf(z0[3] + vb2j[3], 0.f));
            A3.u[2] = pk_bf16(fmaxf(z1[0] + vb2j[4], 0.f), fmaxf(z1[1] + vb2j[5], 0.f));
            A3.u[3] = pk_bf16(fmaxf(z1[2] + vb2j[6], 0.f), fmaxf(z1[3] + vb2j[7], 0.f));

            f32x4 o = {0.f, 0.f, 0.f, 0.f};
            o = __builtin_amdgcn_mfma_f32_16x16x32_bf16(A3.v, bL3, o, 0, 0, 0);
            if (m15 < 6) {
#pragma unroll
                for (int r = 0; r < 4; r++) {
                    long e = g * 32 + st * 16 + quad * 4 + r;
                    if (e < E) out[(size_t)e * 6 + m15] = o[r] + vb3;
                }
            }
        }
        p ^= 1;
    }
#undef LOADIDX
#undef ISSUE
}

extern "C" void kernel_launch(void* const* d_in, const int* in_sizes, int n_in,
                              void* d_out, int out_size, void* d_ws, size_t ws_size,
                              hipStream_t stream) {
    const float* h   = (const float*)d_in[0];
    const int*   src = (const int*)d_in[1];
    const int*   dst = (const int*)d_in[2];
    const float* W1  = (const float*)d_in[3];
    const float* b1  = (const float*)d_in[4];
    const float* W2  = (const float*)d_in[5];
    const float* b2  = (const float*)d_in[6];
    const float* W3  = (const float*)d_in[7];
    const float* b3  = (const float*)d_in[8];

    const int  N = in_sizes[0] / H;     // 100000
    const long E = in_sizes[1];         // 1600000

    char* ws = (char*)d_ws;
    uint16_t* Bfrag = (uint16_t*)ws;                 // 32 KiB
    uint16_t* EFrag = (uint16_t*)(ws + 64 * 1024);   // 5 KiB
    uint16_t* pre   = (uint16_t*)(ws + 128 * 1024);  // N*128*2 = 25.6 MB (bf16)

    prep_weights<<<64, 256, 0, stream>>>(W1, W2, W3, Bfrag, EFrag);
    node_gemm<<<(N + 127) / 128, 256, 0, stream>>>(h, Bfrag, b1, pre, N);
    edge_mlp<<<2048, 128, 0, stream>>>(pre, src, dst, EFrag, b2, b3,
                                       (float*)d_out, E);
}

// Round 11
// 184.904 us; speedup vs baseline: 1.1201x; 1.1201x over previous
//
#include <hip/hip_runtime.h>
#include <hip/hip_bf16.h>
#include <stdint.h>

// Per-edge MLP  out = relu(relu([h[src],h[dst]] @ W1.T + b1) @ W2.T + b2) @ W3.T + b3
// N=100000, H=128, E=1.6M, layers 256->64->32->6, fp32 in/out.
//
// Pipeline:
//  0) prep_weights: W1 -> Bfrag (node_gemm B-frags); W2 -> A-form frags with
//     phi row-permutation; W3 -> B-frag (cols 6..15 zero).
//  1) node_gemm (MFMA): pre[n] = [h@W1a.T + b1 , h@W1b.T] bf16 (25.6MB, L3-res).
//  2) edge_mlp (MFMA): R8's register-gather structure (best measured) fused
//     with R10's transpose trick: layer2 computed as z^T = W2 . y^T with W2 as
//     the MFMA **A** operand (rows permuted by phi_nt(m)=(m>>2)*8+(m&3)+4*nt)
//     and the gathered y as **B** (A/B frag layouts share the same index map,
//     so R8's gather loads are reused verbatim). Lane then holds its layer-3
//     A-fragment IN REGISTERS -> zero LDS, zero bank conflicts, no z roundtrip.
//     Both halves hardware-verified: R8 (gathers) and R10 (compute) pass with
//     identical absmax.
// MFMA 16x16x32_bf16 layouts (m89/m91-verified):
//   A[m=lane&15][k=(lane>>4)*8+j], B[k=(lane>>4)*8+j][n=lane&15],
//   C/D: col=lane&15, row=(lane>>4)*4+reg.

#define H 128

typedef short bf16x8 __attribute__((ext_vector_type(8)));
typedef float f32x4  __attribute__((ext_vector_type(4)));

__device__ __forceinline__ uint16_t f2bf(float f) {           // RNE fp32->bf16
    uint32_t u = __float_as_uint(f);
    return (uint16_t)((u + 0x7fffu + ((u >> 16) & 1u)) >> 16);
}
__device__ __forceinline__ uint32_t pk_bf16(float lo, float hi) {   // RNE pair pack
    __hip_bfloat162 v = __float22bfloat162_rn(float2{lo, hi});
    return *reinterpret_cast<uint32_t*>(&v);
}
__device__ __forceinline__ uint32_t bfadd2_relu(uint32_t a, uint32_t b) {
    __hip_bfloat162 x = *reinterpret_cast<__hip_bfloat162*>(&a);
    __hip_bfloat162 y = *reinterpret_cast<__hip_bfloat162*>(&b);
    __hip_bfloat162 s = __hadd2(x, y);
    uint32_t zu = 0u;                                  // packed bf16 {+0, +0}
    __hip_bfloat162 zero = *reinterpret_cast<__hip_bfloat162*>(&zu);
    __hip_bfloat162 r = __hmax2(s, zero);
    return *reinterpret_cast<uint32_t*>(&r);
}

// ---------------- weight prep ------------------------------------------------
// Bfrag: concat-W1 in B-frag order (node_gemm), 4 ktiles x 8 ntiles (32 KB).
// EFrag (edge_mlp), 5 frags x 64 lanes x 8 bf16:
//   f = nt*2+kt (f<4): layer-2 W2 in **A-frag** form with permuted rows:
//     A[m=lane&15][k] = W2[phi_nt(m)][kt*32+(lane>>4)*8+j],
//     phi_nt(m) = (m>>2)*8 + (m&3) + 4*nt
//   f=4: layer-3 B-frag: B[k=(lane>>4)*8+j][n=lane&15] = (n<6)? W3[n][k] : 0
__global__ void prep_weights(const float* __restrict__ W1,
                             const float* __restrict__ W2,
                             const float* __restrict__ W3,
                             uint16_t* __restrict__ Bfrag,
                             uint16_t* __restrict__ EFrag)
{
    int t = blockIdx.x * blockDim.x + threadIdx.x;
    int stride = gridDim.x * blockDim.x;
    for (int i = t; i < 4 * 8 * 64 * 8; i += stride) {
        int j    = i & 7;
        int lane = (i >> 3) & 63;
        int nt   = (i >> 9) & 7;
        int kt   = (i >> 12);
        int k = kt * 32 + (lane >> 4) * 8 + j;
        int n = nt * 16 + (lane & 15);
        float v = (n < 64) ? W1[n * 256 + k] : W1[(n - 64) * 256 + 128 + k];
        Bfrag[i] = f2bf(v);
    }
    for (int i = t; i < 5 * 64 * 8; i += stride) {
        int j    = i & 7;
        int lane = (i >> 3) & 63;
        int f    = i >> 9;
        uint16_t v;
        if (f < 4) {
            int nt = f >> 1, kt = f & 1;
            int m  = lane & 15;
            int row = (m >> 2) * 8 + (m & 3) + 4 * nt;        // phi_nt(m)
            int col = kt * 32 + (lane >> 4) * 8 + j;
            v = f2bf(W2[row * 64 + col]);
        } else {
            int k = (lane >> 4) * 8 + j;
            int n = lane & 15;
            v = (n < 6) ? f2bf(W3[n * 32 + k]) : (uint16_t)0;
        }
        EFrag[i] = v;
    }
}

// ---------------- per-node precompute (unchanged from R8) --------------------
__global__ void __launch_bounds__(256) node_gemm(
    const float* __restrict__ h,
    const uint16_t* __restrict__ Bfrag,
    const float* __restrict__ b1,
    uint16_t* __restrict__ pre, int N)
{
    const int wave = threadIdx.x >> 6;
    const int lane = threadIdx.x & 63;
    const int n0 = (blockIdx.x * 4 + wave) * 32;
    if (n0 >= N) return;

    const int m    = lane & 15;
    const int quad = lane >> 4;

    bf16x8 afr[2][4];
#pragma unroll
    for (int mt = 0; mt < 2; mt++) {
        int arow = n0 + mt * 16 + m; if (arow >= N) arow = N - 1;  // stores guarded
        const float* hrow = h + (size_t)arow * H + quad * 8;
#pragma unroll
        for (int kt = 0; kt < 4; kt++) {
            float4 lo = *(const float4*)(hrow + kt * 32);
            float4 hi = *(const float4*)(hrow + kt * 32 + 4);
            union { bf16x8 v; uint32_t u[4]; } A;
            A.u[0] = pk_bf16(lo.x, lo.y); A.u[1] = pk_bf16(lo.z, lo.w);
            A.u[2] = pk_bf16(hi.x, hi.y); A.u[3] = pk_bf16(hi.z, hi.w);
            afr[mt][kt] = A.v;
        }
    }

#pragma unroll
    for (int nt = 0; nt < 8; nt++) {
        const int n = nt * 16 + m;
        f32x4 acc0 = {0.f, 0.f, 0.f, 0.f};
        f32x4 acc1 = {0.f, 0.f, 0.f, 0.f};
#pragma unroll
        for (int kt = 0; kt < 4; kt++) {
            bf16x8 bfr = *(const bf16x8*)(Bfrag + ((size_t)(kt * 8 + nt) * 64 + lane) * 8);
            acc0 = __builtin_amdgcn_mfma_f32_16x16x32_bf16(afr[0][kt], bfr, acc0, 0, 0, 0);
            acc1 = __builtin_amdgcn_mfma_f32_16x16x32_bf16(afr[1][kt], bfr, acc1, 0, 0, 0);
        }
        const float bv = (n < 64) ? b1[n] : 0.f;
#pragma unroll
        for (int r = 0; r < 4; r++) {
            const int node0 = n0 + quad * 4 + r;
            if (node0 < N) pre[(size_t)node0 * H + n] = f2bf(acc0[r] + bv);
            const int node1 = n0 + 16 + quad * 4 + r;
            if (node1 < N) pre[(size_t)node1 * H + n] = f2bf(acc1[r] + bv);
        }
    }
}

// ---------------- per-edge MLP: register gathers + transpose trick, no LDS ---
// 64 edges/wave (4 subtiles of 16). All 16 gathers issued upfront in flat regs
// (R8 structure); per subtile: y = relu(pa+pb) packed bf16 -> layer2 as
// z^T = W2(A) x y(B) -> A3 packed in-register -> layer3 MFMA -> store.
__global__ void __launch_bounds__(256) edge_mlp(
    const uint16_t* __restrict__ pre,
    const int* __restrict__ src, const int* __restrict__ dst,
    const uint16_t* __restrict__ EFrag,
    const float* __restrict__ b2, const float* __restrict__ b3,
    float* __restrict__ out, long E)
{
    const int lane = threadIdx.x & 63;
    const int m15  = lane & 15;
    const int quad = lane >> 4;

    // Weights: W2-as-A frags (f=nt*2+kt), W3 B-frag; per-lane biases.
    bf16x8 w2a[4], bL3;
#pragma unroll
    for (int f = 0; f < 4; f++) w2a[f] = *(const bf16x8*)(EFrag + (f * 64 + lane) * 8);
    bL3 = *(const bf16x8*)(EFrag + (4 * 64 + lane) * 8);
    float vb2j[8];
    {
        float4 t0 = *(const float4*)(b2 + quad * 8);
        float4 t1 = *(const float4*)(b2 + quad * 8 + 4);
        vb2j[0] = t0.x; vb2j[1] = t0.y; vb2j[2] = t0.z; vb2j[3] = t0.w;
        vb2j[4] = t1.x; vb2j[5] = t1.y; vb2j[6] = t1.z; vb2j[7] = t1.w;
    }
    const float vb3 = (m15 < 6) ? b3[m15] : 0.f;

    const long e0 = (long)(blockIdx.x * 4 + (threadIdx.x >> 6)) * 64;
    if (e0 >= E) return;

    // ---- issue ALL 16 gathers upfront: flat regs, 32-bit byte offsets -------
    const char* preb = (const char*)pre;
    uint32_t oa0, oa1, oa2, oa3, ob0, ob1, ob2, ob3;
    {
        long ea = e0 + m15;           // subtile st uses edge e0+st*16+m15
        long eb = (ea + 16 < E) ? ea + 16 : E - 1;
        long ec = (ea + 32 < E) ? ea + 32 : E - 1;
        long ed = (ea + 48 < E) ? ea + 48 : E - 1;
        if (ea >= E) ea = E - 1;
        oa0 = (uint32_t)src[ea] * 256u + (uint32_t)quad * 16u;
        ob0 = (uint32_t)dst[ea] * 256u + 128u + (uint32_t)quad * 16u;
        oa1 = (uint32_t)src[eb] * 256u + (uint32_t)quad * 16u;
        ob1 = (uint32_t)dst[eb] * 256u + 128u + (uint32_t)quad * 16u;
        oa2 = (uint32_t)src[ec] * 256u + (uint32_t)quad * 16u;
        ob2 = (uint32_t)dst[ec] * 256u + 128u + (uint32_t)quad * 16u;
        oa3 = (uint32_t)src[ed] * 256u + (uint32_t)quad * 16u;
        ob3 = (uint32_t)dst[ed] * 256u + 128u + (uint32_t)quad * 16u;
    }
    uint4 a00 = *(const uint4*)(preb + oa0);
    uint4 a01 = *(const uint4*)(preb + oa0 + 64);
    uint4 b00 = *(const uint4*)(preb + ob0);
    uint4 b01 = *(const uint4*)(preb + ob0 + 64);
    uint4 a10 = *(const uint4*)(preb + oa1);
    uint4 a11 = *(const uint4*)(preb + oa1 + 64);
    uint4 b10 = *(const uint4*)(preb + ob1);
    uint4 b11 = *(const uint4*)(preb + ob1 + 64);
    uint4 a20 = *(const uint4*)(preb + oa2);
    uint4 a21 = *(const uint4*)(preb + oa2 + 64);
    uint4 b20 = *(const uint4*)(preb + ob2);
    uint4 b21 = *(const uint4*)(preb + ob2 + 64);
    uint4 a30 = *(const uint4*)(preb + oa3);
    uint4 a31 = *(const uint4*)(preb + oa3 + 64);
    uint4 b30 = *(const uint4*)(preb + ob3);
    uint4 b31 = *(const uint4*)(preb + ob3 + 64);

    // ---- per subtile: y(B-frags) -> z^T (W2-as-A) -> A3 -> layer3 -> store --
#define DO_SUBTILE(ST, UA0, UB0, UA1, UB1)                                        \
    {                                                                             \
        union { bf16x8 v; uint32_t u[4]; } Y0, Y1;                                \
        Y0.u[0] = bfadd2_relu(UA0.x, UB0.x);                                      \
        Y0.u[1] = bfadd2_relu(UA0.y, UB0.y);                                      \
        Y0.u[2] = bfadd2_relu(UA0.z, UB0.z);                                      \
        Y0.u[3] = bfadd2_relu(UA0.w, UB0.w);                                      \
        Y1.u[0] = bfadd2_relu(UA1.x, UB1.x);                                      \
        Y1.u[1] = bfadd2_relu(UA1.y, UB1.y);                                      \
        Y1.u[2] = bfadd2_relu(UA1.z, UB1.z);                                      \
        Y1.u[3] = bfadd2_relu(UA1.w, UB1.w);                                      \
        f32x4 z0 = {0.f, 0.f, 0.f, 0.f};   /* features quad*8 + r     */          \
        f32x4 z1 = {0.f, 0.f, 0.f, 0.f};   /* features quad*8 + 4 + r */          \
        z0 = __builtin_amdgcn_mfma_f32_16x16x32_bf16(w2a[0], Y0.v, z0, 0, 0, 0);  \
        z0 = __builtin_amdgcn_mfma_f32_16x16x32_bf16(w2a[1], Y1.v, z0, 0, 0, 0);  \
        z1 = __builtin_amdgcn_mfma_f32_16x16x32_bf16(w2a[2], Y0.v, z1, 0, 0, 0);  \
        z1 = __builtin_amdgcn_mfma_f32_16x16x32_bf16(w2a[3], Y1.v, z1, 0, 0, 0);  \
        union { bf16x8 v; uint32_t u[4]; } A3;                                    \
        A3.u[0] = pk_bf16(fmaxf(z0[0] + vb2j[0], 0.f), fmaxf(z0[1] + vb2j[1], 0.f)); \
        A3.u[1] = pk_bf16(fmaxf(z0[2] + vb2j[2], 0.f), fmaxf(z0[3] + vb2j[3], 0.f)); \
        A3.u[2] = pk_bf16(fmaxf(z1[0] + vb2j[4], 0.f), fmaxf(z1[1] + vb2j[5], 0.f)); \
        A3.u[3] = pk_bf16(fmaxf(z1[2] + vb2j[6], 0.f), fmaxf(z1[3] + vb2j[7], 0.f)); \
        f32x4 o = {0.f, 0.f, 0.f, 0.f};                                           \
        o = __builtin_amdgcn_mfma_f32_16x16x32_bf16(A3.v, bL3, o, 0, 0, 0);       \
        if (m15 < 6) {                                                            \
            _Pragma("unroll")                                                     \
            for (int r = 0; r < 4; r++) {                                         \
                long e = e0 + (ST) * 16 + quad * 4 + r;                           \
                if (e < E) out[(size_t)e * 6 + m15] = o[r] + vb3;                 \
            }                                                                     \
        }                                                                         \
    }

    DO_SUBTILE(0, a00, b00, a01, b01)
    DO_SUBTILE(1, a10, b10, a11, b11)
    DO_SUBTILE(2, a20, b20, a21, b21)
    DO_SUBTILE(3, a30, b30, a31, b31)
#undef DO_SUBTILE
}

extern "C" void kernel_launch(void* const* d_in, const int* in_sizes, int n_in,
                              void* d_out, int out_size, void* d_ws, size_t ws_size,
                              hipStream_t stream) {
    const float* h   = (const float*)d_in[0];
    const int*   src = (const int*)d_in[1];
    const int*   dst = (const int*)d_in[2];
    const float* W1  = (const float*)d_in[3];
    const float* b1  = (const float*)d_in[4];
    const float* W2  = (const float*)d_in[5];
    const float* b2  = (const float*)d_in[6];
    const float* W3  = (const float*)d_in[7];
    const float* b3  = (const float*)d_in[8];

    const int  N = in_sizes[0] / H;     // 100000
    const long E = in_sizes[1];         // 1600000

    char* ws = (char*)d_ws;
    uint16_t* Bfrag = (uint16_t*)ws;                 // 32 KiB
    uint16_t* EFrag = (uint16_t*)(ws + 64 * 1024);   // 5 KiB
    uint16_t* pre   = (uint16_t*)(ws + 128 * 1024);  // N*128*2 = 25.6 MB (bf16)

    prep_weights<<<64, 256, 0, stream>>>(W1, W2, W3, Bfrag, EFrag);
    node_gemm<<<(N + 127) / 128, 256, 0, stream>>>(h, Bfrag, b1, pre, N);
    const int eblocks = (int)((E + 255) / 256);      // 4 waves x 64 edges per block
    edge_mlp<<<eblocks, 256, 0, stream>>>(pre, src, dst, EFrag, b2, b3,
                                          (float*)d_out, E);
}